// Round 2
// baseline (1583.804 us; speedup 1.0000x reference)
//
#include <hip/hip_runtime.h>
#include <cmath>

#define NPTS 256
#define TOTPTS 32768
#define KNB 16

// ---------------- workspace layout (float-element offsets) ----------------
static const size_t OFF_HA   = 0;
static const size_t OFF_HB   = 4194304;
static const size_t OFF_UZ   = 6291456;
static const size_t OFF_YMAX = 23068672;
static const size_t OFF_YMIN = 31457280;
static const size_t OFF_IDX  = 39845888;
static const size_t OFF_VT   = 40370176;
static const size_t OFF_SUMS = 40458240;   // byte offset 161,832,960 (8-aligned)

__device__ __forceinline__ float gelu_erf(float v) {
  return 0.5f * v * (1.0f + erff(v * 0.70710678118654752f));
}

// ---------------- prep: transpose x -> h0, build Vt, zero stats ----------------
__global__ __launch_bounds__(256) void prep_kernel(
    const float* __restrict__ x, float* __restrict__ h0,
    const float* __restrict__ W1, const float* __restrict__ W2, const float* __restrict__ W3,
    const float* __restrict__ W4, const float* __restrict__ W5,
    float* __restrict__ Vt, double* __restrict__ sums) {
  const int stride = gridDim.x * blockDim.x;
  const int tid0 = blockIdx.x * blockDim.x + threadIdx.x;
  // x: (4,6,32,256) -> h0: (128 clouds, 256 pts, 6 ch)
  for (int id = tid0; id < 196608; id += stride) {
    int ch = id % 6;
    int r  = id / 6;            // r = cloud*256 + s
    int s  = r & 255;
    int p  = (r >> 8) & 31;
    int bs = r >> 13;
    h0[id] = x[(((size_t)(bs * 6 + ch) * 32 + p) << 8) + s];
  }
  // Vt[l]: (Cin x 2O), Vt[c*2O + j] = W[j<O ? j*2Cin+c : (j-O)*2Cin+Cin+c]
  for (int id = tid0; id < 87232; id += stride) {
    const float* W; int K, N2, base;
    if (id < 192)        { W = W1; K = 6;   N2 = 32;  base = 0; }
    else if (id < 1216)  { W = W2; K = 16;  N2 = 64;  base = 192; }
    else if (id < 5312)  { W = W3; K = 32;  N2 = 128; base = 1216; }
    else if (id < 21696) { W = W4; K = 64;  N2 = 256; base = 5312; }
    else                 { W = W5; K = 128; N2 = 512; base = 21696; }
    int e = id - base;
    int c = e / N2;
    int j = e - c * N2;
    int O = N2 >> 1;
    Vt[id] = (j < O) ? W[j * 2 * K + c] : W[(j - O) * 2 * K + K + c];
  }
  for (int id = tid0; id < 992; id += stride) sums[id] = 0.0;
}

// ---------------- knn: per-row top-16 of 2*inner - sq_i - sq_j (fp64-exact) ----
template<int C>
__global__ __launch_bounds__(128) void knn_kernel(const float* __restrict__ h,
                                                  int* __restrict__ idxout) {
  constexpr int SP = (C + 4) & ~3;   // padded row stride
  constexpr int JT = 64;             // j-tile
  __shared__ float pts[JT * SP];
  __shared__ double sqs[JT];
  const int b = blockIdx.x >> 1;
  const int t = (blockIdx.x & 1) * 128 + (int)threadIdx.x;   // my query row
  const float* hb = h + (size_t)b * NPTS * C;

  float reg[C];
  #pragma unroll
  for (int c = 0; c < C; ++c) reg[c] = hb[(size_t)t * C + c];
  double q0 = 0.0, q1 = 0.0;
  #pragma unroll
  for (int c = 0; c + 1 < C; c += 2) {
    q0 = fma((double)reg[c],   (double)reg[c],   q0);
    q1 = fma((double)reg[c+1], (double)reg[c+1], q1);
  }
  #pragma unroll
  for (int c = C & ~1; c < C; ++c) q0 = fma((double)reg[c], (double)reg[c], q0);
  const double sqt = q0 + q1;

  double tv[KNB]; int ti[KNB];
  #pragma unroll
  for (int s = 0; s < KNB; ++s) { tv[s] = -INFINITY; ti[s] = 0; }

  for (int tile = 0; tile < NPTS / JT; ++tile) {
    __syncthreads();
    for (int e = threadIdx.x; e < JT * C; e += 128) {
      int r = e / C, c = e - r * C;
      pts[r * SP + c] = hb[(size_t)(tile * JT + r) * C + c];
    }
    __syncthreads();
    if (threadIdx.x < JT) {
      double s0 = 0.0;
      #pragma unroll 4
      for (int c = 0; c < C; ++c) {
        double v = (double)pts[threadIdx.x * SP + c];
        s0 = fma(v, v, s0);
      }
      sqs[threadIdx.x] = s0;
    }
    __syncthreads();
    for (int jj = 0; jj < JT; ++jj) {
      const float* pr = pts + jj * SP;
      double d0 = 0.0, d1 = 0.0;
      #pragma unroll
      for (int c = 0; c + 1 < C; c += 2) {
        d0 = fma((double)reg[c],   (double)pr[c],   d0);
        d1 = fma((double)reg[c+1], (double)pr[c+1], d1);
      }
      #pragma unroll
      for (int c = C & ~1; c < C; ++c) d0 = fma((double)reg[c], (double)pr[c], d0);
      double nd = 2.0 * (d0 + d1) - sqt - sqs[jj];
      if (nd > tv[KNB - 1]) {     // strict > : keeps lowest index on ties (lax.top_k)
        int j = tile * JT + jj;
        #pragma unroll
        for (int s = KNB - 1; s >= 1; --s) {
          bool up   = nd > tv[s - 1];
          bool here = nd > tv[s];
          double pv = tv[s - 1]; int pi = ti[s - 1];
          tv[s] = up ? pv : (here ? nd : tv[s]);
          ti[s] = up ? pi : (here ? j  : ti[s]);
        }
        if (nd > tv[0]) { tv[0] = nd; ti[0] = j; }
      }
    }
  }
  int* op = idxout + (size_t)(b * NPTS + t) * KNB;
  #pragma unroll
  for (int s = 0; s < KNB; ++s) op[s] = b * NPTS + ti[s];
}

// ---------------- GEMM: UZ(32768 x 2O) = h(32768 x K) * Vt(K x 2O) ----------------
template<int K, int N2>
__global__ __launch_bounds__(256) void gemm_uz_kernel(const float* __restrict__ h,
                                                      const float* __restrict__ Vt,
                                                      float* __restrict__ UZ) {
  constexpr int KC = 32;
  constexpr int NBLK = (N2 + 63) / 64;
  __shared__ __align__(16) float As[KC * 68];   // [k][m]
  __shared__ __align__(16) float Bs[KC * 68];   // [k][j]
  const int m0 = (int)(blockIdx.x / NBLK) * 64;
  const int n0 = (int)(blockIdx.x % NBLK) * 64;
  const int tid = threadIdx.x;
  const int mm = (tid & 15) * 4;
  const int jj = (tid >> 4) * 4;
  float acc[4][4] = {{0.f}};
  for (int k0 = 0; k0 < K; k0 += KC) {
    #pragma unroll
    for (int e = tid; e < 64 * KC; e += 256) {
      int am = e / KC, ac = e - am * KC;
      float v = 0.f;
      if (k0 + ac < K) v = h[(size_t)(m0 + am) * K + k0 + ac];
      As[ac * 68 + am] = v;
    }
    #pragma unroll
    for (int e = tid; e < KC * 64; e += 256) {
      int bj = e & 63, bc = e >> 6;
      float v = 0.f;
      if (k0 + bc < K && n0 + bj < N2) v = Vt[(size_t)(k0 + bc) * N2 + n0 + bj];
      Bs[bc * 68 + bj] = v;
    }
    __syncthreads();
    #pragma unroll
    for (int c = 0; c < KC; ++c) {
      float4 av = *(const float4*)(As + c * 68 + mm);
      float4 bv = *(const float4*)(Bs + c * 68 + jj);
      acc[0][0] = fmaf(av.x, bv.x, acc[0][0]);
      acc[0][1] = fmaf(av.x, bv.y, acc[0][1]);
      acc[0][2] = fmaf(av.x, bv.z, acc[0][2]);
      acc[0][3] = fmaf(av.x, bv.w, acc[0][3]);
      acc[1][0] = fmaf(av.y, bv.x, acc[1][0]);
      acc[1][1] = fmaf(av.y, bv.y, acc[1][1]);
      acc[1][2] = fmaf(av.y, bv.z, acc[1][2]);
      acc[1][3] = fmaf(av.y, bv.w, acc[1][3]);
      acc[2][0] = fmaf(av.z, bv.x, acc[2][0]);
      acc[2][1] = fmaf(av.z, bv.y, acc[2][1]);
      acc[2][2] = fmaf(av.z, bv.z, acc[2][2]);
      acc[2][3] = fmaf(av.z, bv.w, acc[2][3]);
      acc[3][0] = fmaf(av.w, bv.x, acc[3][0]);
      acc[3][1] = fmaf(av.w, bv.y, acc[3][1]);
      acc[3][2] = fmaf(av.w, bv.z, acc[3][2]);
      acc[3][3] = fmaf(av.w, bv.w, acc[3][3]);
    }
    __syncthreads();
  }
  if (n0 + jj < N2) {
    #pragma unroll
    for (int i = 0; i < 4; ++i) {
      float4 v = make_float4(acc[i][0], acc[i][1], acc[i][2], acc[i][3]);
      *(float4*)(UZ + (size_t)(m0 + mm + i) * N2 + n0 + jj) = v;
    }
  }
}

// ---------------- combine: gather u rows, max/min + stats ----------------
template<int O>
__global__ __launch_bounds__(256) void combine_kernel(const float* __restrict__ UZ,
    const int* __restrict__ idx, const float* __restrict__ bias,
    float* __restrict__ ymax, float* __restrict__ ymin, double* __restrict__ sums) {
  constexpr int PPI = 256 / O;          // points per iteration
  constexpr int PPB = TOTPTS / 256;     // 128 points per block
  constexpr int ITERS = PPB / PPI;
  __shared__ double red[256];
  const int o = threadIdx.x % O;
  const int sub = threadIdx.x / O;
  const int base = blockIdx.x * PPB;
  double a1 = 0.0, a2 = 0.0;
  for (int it = 0; it < ITERS; ++it) {
    int n = base + it * PPI + sub;
    const int* ip = idx + (size_t)n * KNB;
    float un = UZ[(size_t)n * (2 * O) + o];
    float zn = UZ[(size_t)n * (2 * O) + O + o];
    float w = zn - un + bias[o];
    float mx = -INFINITY, mn = INFINITY, s1 = 0.f, s2 = 0.f;
    #pragma unroll
    for (int kk = 0; kk < KNB; ++kk) {
      int j = ip[kk];
      float uv = UZ[(size_t)j * (2 * O) + o];
      mx = fmaxf(mx, uv);
      mn = fminf(mn, uv);
      s1 += uv;
      s2 = fmaf(uv, uv, s2);
    }
    ymax[(size_t)n * O + o] = mx + w;
    ymin[(size_t)n * O + o] = mn + w;
    a1 += (double)(s1 + 16.f * w);
    a2 += (double)(s2 + 2.f * w * s1 + 16.f * (w * w));
  }
  red[threadIdx.x] = a1;
  __syncthreads();
  if (threadIdx.x < O) {
    double t = red[threadIdx.x];
    #pragma unroll
    for (int q = 1; q < PPI; ++q) t += red[threadIdx.x + q * O];
    atomicAdd(&sums[threadIdx.x], t);
  }
  __syncthreads();
  red[threadIdx.x] = a2;
  __syncthreads();
  if (threadIdx.x < O) {
    double t = red[threadIdx.x];
    #pragma unroll
    for (int q = 1; q < PPI; ++q) t += red[threadIdx.x + q * O];
    atomicAdd(&sums[O + threadIdx.x], t);
  }
}

// ---------------- apply: BN affine + erf-GELU + endpoint max ----------------
template<int O>
__global__ __launch_bounds__(256) void apply_kernel(const float* __restrict__ ymax,
    const float* __restrict__ ymin, const double* __restrict__ sums,
    const float* __restrict__ g, const float* __restrict__ bt, float* __restrict__ hout) {
  const int tid = blockIdx.x * 256 + threadIdx.x;
  const int o = tid & (O - 1);
  double m = sums[o] * (1.0 / 524288.0);
  double v = fma(-m, m, sums[O + o] * (1.0 / 524288.0));
  float A = g[o] / sqrtf((float)v + 1e-5f);
  float Cc = fmaf(-(float)m, A, bt[o]);
  float r1 = gelu_erf(fmaf(A, ymax[tid], Cc));
  float r2 = gelu_erf(fmaf(A, ymin[tid], Cc));
  hout[tid] = fmaxf(r1, r2);
}

// layer-5 apply, transposes (n,o) -> (bs, o, p, s) via LDS tile
__global__ __launch_bounds__(256) void apply_final_kernel(const float* __restrict__ ymax,
    const float* __restrict__ ymin, const double* __restrict__ sums,
    const float* __restrict__ g, const float* __restrict__ bt, float* __restrict__ out) {
  constexpr int O = 256;
  __shared__ float tile[64 * 65];
  const int bo = blockIdx.x & 3;
  const int bn = blockIdx.x >> 2;
  const int n0 = bn * 64, o0 = bo * 64;
  const int lane = threadIdx.x & 63;
  const int grp = threadIdx.x >> 6;
  {
    const int oc = o0 + lane;
    double m = sums[oc] * (1.0 / 524288.0);
    double v = fma(-m, m, sums[O + oc] * (1.0 / 524288.0));
    float A = g[oc] / sqrtf((float)v + 1e-5f);
    float Cc = fmaf(-(float)m, A, bt[oc]);
    #pragma unroll
    for (int q = 0; q < 16; ++q) {
      int r = grp * 16 + q;
      size_t src = (size_t)(n0 + r) * O + oc;
      float r1 = gelu_erf(fmaf(A, ymax[src], Cc));
      float r2 = gelu_erf(fmaf(A, ymin[src], Cc));
      tile[r * 65 + lane] = fmaxf(r1, r2);
    }
  }
  __syncthreads();
  const int s0 = n0 & 255;
  const int p  = (n0 >> 8) & 31;
  const int bs = n0 >> 13;
  size_t basei = ((size_t)(bs * 256 + o0) * 32 + p) * 256 + s0;
  #pragma unroll
  for (int q = 0; q < 16; ++q) {
    int c = grp * 16 + q;
    out[basei + (size_t)c * 8192 + lane] = tile[lane * 65 + c];
  }
}

// ---------------- launch ----------------
extern "C" void kernel_launch(void* const* d_in, const int* in_sizes, int n_in,
                              void* d_out, int out_size, void* d_ws, size_t ws_size,
                              hipStream_t stream) {
  (void)in_sizes; (void)n_in; (void)out_size; (void)ws_size;
  const float* x   = (const float*)d_in[0];
  const float* W1  = (const float*)d_in[1];
  const float* b1  = (const float*)d_in[2];
  const float* g1  = (const float*)d_in[3];
  const float* bt1 = (const float*)d_in[4];
  const float* W2  = (const float*)d_in[5];
  const float* b2  = (const float*)d_in[6];
  const float* g2  = (const float*)d_in[7];
  const float* bt2 = (const float*)d_in[8];
  const float* W3  = (const float*)d_in[9];
  const float* b3  = (const float*)d_in[10];
  const float* g3  = (const float*)d_in[11];
  const float* bt3 = (const float*)d_in[12];
  const float* W4  = (const float*)d_in[13];
  const float* b4  = (const float*)d_in[14];
  const float* g4  = (const float*)d_in[15];
  const float* bt4 = (const float*)d_in[16];
  const float* W5  = (const float*)d_in[17];
  const float* b5  = (const float*)d_in[18];
  const float* g5  = (const float*)d_in[19];
  const float* bt5 = (const float*)d_in[20];

  float* ws   = (float*)d_ws;
  float* hA   = ws + OFF_HA;
  float* hB   = ws + OFF_HB;
  float* UZ   = ws + OFF_UZ;
  float* ymx  = ws + OFF_YMAX;
  float* ymn  = ws + OFF_YMIN;
  int*   idxb = (int*)(ws + OFF_IDX);
  float* Vt   = ws + OFF_VT;
  double* sums = (double*)(ws + OFF_SUMS);

  prep_kernel<<<256, 256, 0, stream>>>(x, hA, W1, W2, W3, W4, W5, Vt, sums);

  // layer 1: hA (C=6) -> hB (O=16)
  knn_kernel<6><<<256, 128, 0, stream>>>(hA, idxb);
  gemm_uz_kernel<6, 32><<<512, 256, 0, stream>>>(hA, Vt + 0, UZ);
  combine_kernel<16><<<256, 256, 0, stream>>>(UZ, idxb, b1, ymx, ymn, sums + 0);
  apply_kernel<16><<<2048, 256, 0, stream>>>(ymx, ymn, sums + 0, g1, bt1, hB);

  // layer 2: hB (C=16) -> hA (O=32)
  knn_kernel<16><<<256, 128, 0, stream>>>(hB, idxb);
  gemm_uz_kernel<16, 64><<<512, 256, 0, stream>>>(hB, Vt + 192, UZ);
  combine_kernel<32><<<256, 256, 0, stream>>>(UZ, idxb, b2, ymx, ymn, sums + 32);
  apply_kernel<32><<<4096, 256, 0, stream>>>(ymx, ymn, sums + 32, g2, bt2, hA);

  // layer 3: hA (C=32) -> hB (O=64)
  knn_kernel<32><<<256, 128, 0, stream>>>(hA, idxb);
  gemm_uz_kernel<32, 128><<<1024, 256, 0, stream>>>(hA, Vt + 1216, UZ);
  combine_kernel<64><<<256, 256, 0, stream>>>(UZ, idxb, b3, ymx, ymn, sums + 96);
  apply_kernel<64><<<8192, 256, 0, stream>>>(ymx, ymn, sums + 96, g3, bt3, hB);

  // layer 4: hB (C=64) -> hA (O=128)
  knn_kernel<64><<<256, 128, 0, stream>>>(hB, idxb);
  gemm_uz_kernel<64, 256><<<2048, 256, 0, stream>>>(hB, Vt + 5312, UZ);
  combine_kernel<128><<<256, 256, 0, stream>>>(UZ, idxb, b4, ymx, ymn, sums + 224);
  apply_kernel<128><<<16384, 256, 0, stream>>>(ymx, ymn, sums + 224, g4, bt4, hA);

  // layer 5: hA (C=128) -> d_out (O=256, transposed layout)
  knn_kernel<128><<<256, 128, 0, stream>>>(hA, idxb);
  gemm_uz_kernel<128, 512><<<4096, 256, 0, stream>>>(hA, Vt + 21696, UZ);
  combine_kernel<256><<<256, 256, 0, stream>>>(UZ, idxb, b5, ymx, ymn, sums + 480);
  apply_final_kernel<<<2048, 256, 0, stream>>>(ymx, ymn, sums + 480, g5, bt5, (float*)d_out);
}

// Round 3
// 1287.028 us; speedup vs baseline: 1.2306x; 1.2306x over previous
//
#include <hip/hip_runtime.h>
#include <cmath>

#define NPTS 256
#define TOTPTS 32768
#define KNB 16

// ---------------- workspace layout (float-element offsets) ----------------
// UZ region doubles as the per-layer fp64 neg-dist matrix (64 MiB) during knn.
// YMAX region's head doubles as per-point fp64 sq norms (256 KiB) during knn.
static const size_t OFF_HA   = 0;
static const size_t OFF_HB   = 4194304;
static const size_t OFF_UZ   = 6291456;
static const size_t OFF_YMAX = 23068672;
static const size_t OFF_YMIN = 31457280;
static const size_t OFF_IDX  = 39845888;
static const size_t OFF_VT   = 40370176;
static const size_t OFF_SUMS = 40458240;   // byte offset 161,832,960 (8-aligned)

__device__ __forceinline__ float gelu_erf(float v) {
  return 0.5f * v * (1.0f + erff(v * 0.70710678118654752f));
}

// ---------------- prep: transpose x -> h0, build Vt, zero stats ----------------
__global__ __launch_bounds__(256) void prep_kernel(
    const float* __restrict__ x, float* __restrict__ h0,
    const float* __restrict__ W1, const float* __restrict__ W2, const float* __restrict__ W3,
    const float* __restrict__ W4, const float* __restrict__ W5,
    float* __restrict__ Vt, double* __restrict__ sums) {
  const int stride = gridDim.x * blockDim.x;
  const int tid0 = blockIdx.x * blockDim.x + threadIdx.x;
  // x: (4,6,32,256) -> h0: (128 clouds, 256 pts, 6 ch)
  for (int id = tid0; id < 196608; id += stride) {
    int ch = id % 6;
    int r  = id / 6;            // r = cloud*256 + s
    int s  = r & 255;
    int p  = (r >> 8) & 31;
    int bs = r >> 13;
    h0[id] = x[(((size_t)(bs * 6 + ch) * 32 + p) << 8) + s];
  }
  // Vt[l]: (Cin x 2O), Vt[c*2O + j] = W[j<O ? j*2Cin+c : (j-O)*2Cin+Cin+c]
  for (int id = tid0; id < 87232; id += stride) {
    const float* W; int K, N2, base;
    if (id < 192)        { W = W1; K = 6;   N2 = 32;  base = 0; }
    else if (id < 1216)  { W = W2; K = 16;  N2 = 64;  base = 192; }
    else if (id < 5312)  { W = W3; K = 32;  N2 = 128; base = 1216; }
    else if (id < 21696) { W = W4; K = 64;  N2 = 256; base = 5312; }
    else                 { W = W5; K = 128; N2 = 512; base = 21696; }
    int e = id - base;
    int c = e / N2;
    int j = e - c * N2;
    int O = N2 >> 1;
    Vt[id] = (j < O) ? W[j * 2 * K + c] : W[(j - O) * 2 * K + K + c];
  }
  for (int id = tid0; id < 992; id += stride) sums[id] = 0.0;
}

// ---------------- sq: per-point fp64 squared norm ----------------
template<int C>
__global__ __launch_bounds__(256) void sq_kernel(const float* __restrict__ h,
                                                 double* __restrict__ sqd) {
  const int n = blockIdx.x * 256 + threadIdx.x;
  const float* p = h + (size_t)n * C;
  double q0 = 0.0, q1 = 0.0;
  #pragma unroll
  for (int c = 0; c + 1 < C; c += 2) {
    q0 = fma((double)p[c],   (double)p[c],   q0);
    q1 = fma((double)p[c+1], (double)p[c+1], q1);
  }
  #pragma unroll
  for (int c = C & ~1; c < C; ++c) q0 = fma((double)p[c], (double)p[c], q0);
  sqd[n] = q0 + q1;
}

// ---------------- dist: fp64 neg-dist matrix, register-tiled GEMM ----------------
// nd[cloud][i][j] = 2*<h_i,h_j> - sq_i - sq_j  (exact ranking key, fp64)
// grid: 128 clouds x 16 tiles (4x4 grid of 64x64 tiles), 256 threads
template<int K>
__global__ __launch_bounds__(256) void dist_kernel(const float* __restrict__ h,
                                                   const double* __restrict__ sqd,
                                                   double* __restrict__ nd) {
  constexpr int KC = (K < 32) ? K : 32;
  __shared__ __align__(16) float As[KC * 68];   // [k][i]
  __shared__ __align__(16) float Bs[KC * 68];   // [k][j]
  const int cloud = blockIdx.x >> 4;
  const int tile  = blockIdx.x & 15;
  const int i0 = (tile >> 2) * 64;
  const int j0 = (tile & 3) * 64;
  const float* hb = h + (size_t)cloud * NPTS * K;
  const int tid = threadIdx.x;
  const int mm = (tid & 15) * 4;
  const int jj = (tid >> 4) * 4;
  double acc[4][4] = {{0.0}};
  for (int k0 = 0; k0 < K; k0 += KC) {
    for (int e = tid; e < 64 * KC; e += 256) {
      int am = e / KC, ac = e - am * KC;
      As[ac * 68 + am] = hb[(size_t)(i0 + am) * K + k0 + ac];
    }
    for (int e = tid; e < 64 * KC; e += 256) {
      int bm = e / KC, bc = e - bm * KC;
      Bs[bc * 68 + bm] = hb[(size_t)(j0 + bm) * K + k0 + bc];
    }
    __syncthreads();
    #pragma unroll
    for (int c = 0; c < KC; ++c) {
      float4 av = *(const float4*)(As + c * 68 + mm);
      float4 bv = *(const float4*)(Bs + c * 68 + jj);
      double a0 = (double)av.x, a1 = (double)av.y, a2 = (double)av.z, a3 = (double)av.w;
      double b0 = (double)bv.x, b1 = (double)bv.y, b2 = (double)bv.z, b3 = (double)bv.w;
      acc[0][0] = fma(a0, b0, acc[0][0]);
      acc[0][1] = fma(a0, b1, acc[0][1]);
      acc[0][2] = fma(a0, b2, acc[0][2]);
      acc[0][3] = fma(a0, b3, acc[0][3]);
      acc[1][0] = fma(a1, b0, acc[1][0]);
      acc[1][1] = fma(a1, b1, acc[1][1]);
      acc[1][2] = fma(a1, b2, acc[1][2]);
      acc[1][3] = fma(a1, b3, acc[1][3]);
      acc[2][0] = fma(a2, b0, acc[2][0]);
      acc[2][1] = fma(a2, b1, acc[2][1]);
      acc[2][2] = fma(a2, b2, acc[2][2]);
      acc[2][3] = fma(a2, b3, acc[2][3]);
      acc[3][0] = fma(a3, b0, acc[3][0]);
      acc[3][1] = fma(a3, b1, acc[3][1]);
      acc[3][2] = fma(a3, b2, acc[3][2]);
      acc[3][3] = fma(a3, b3, acc[3][3]);
    }
    __syncthreads();
  }
  double sqi[4], sqj[4];
  #pragma unroll
  for (int r = 0; r < 4; ++r) sqi[r] = sqd[cloud * NPTS + i0 + mm + r];
  #pragma unroll
  for (int s = 0; s < 4; ++s) sqj[s] = sqd[cloud * NPTS + j0 + jj + s];
  double* orow = nd + (size_t)cloud * NPTS * NPTS;
  #pragma unroll
  for (int r = 0; r < 4; ++r) {
    double v0 = 2.0 * acc[r][0] - sqi[r] - sqj[0];
    double v1 = 2.0 * acc[r][1] - sqi[r] - sqj[1];
    double v2 = 2.0 * acc[r][2] - sqi[r] - sqj[2];
    double v3 = 2.0 * acc[r][3] - sqi[r] - sqj[3];
    double* p = orow + (size_t)(i0 + mm + r) * NPTS + j0 + jj;
    *(double2*)(p)     = make_double2(v0, v1);
    *(double2*)(p + 2) = make_double2(v2, v3);
  }
}

// ---------------- topk: per-row top-16 streaming insertion (fp64) ----------------
__global__ __launch_bounds__(64) void topk_kernel(const double* __restrict__ nd,
                                                  int* __restrict__ idxout) {
  const int n = blockIdx.x * 64 + (int)threadIdx.x;
  const double* row = nd + (size_t)n * NPTS;
  double tv[KNB]; int ti[KNB];
  #pragma unroll
  for (int s = 0; s < KNB; ++s) { tv[s] = -INFINITY; ti[s] = 0; }
  for (int j0 = 0; j0 < NPTS; j0 += 4) {
    double2 a = *(const double2*)(row + j0);
    double2 b = *(const double2*)(row + j0 + 2);
    double vals[4] = {a.x, a.y, b.x, b.y};
    #pragma unroll
    for (int q = 0; q < 4; ++q) {
      double v = vals[q];
      if (v > tv[KNB - 1]) {   // strict > : keeps lowest index on ties (lax.top_k)
        int j = j0 + q;
        #pragma unroll
        for (int s = KNB - 1; s >= 1; --s) {
          bool up   = v > tv[s - 1];
          bool here = v > tv[s];
          double pv = tv[s - 1]; int pi = ti[s - 1];
          tv[s] = up ? pv : (here ? v : tv[s]);
          ti[s] = up ? pi : (here ? j : ti[s]);
        }
        if (v > tv[0]) { tv[0] = v; ti[0] = j; }
      }
    }
  }
  const int base = n & ~(NPTS - 1);
  int* op = idxout + (size_t)n * KNB;
  #pragma unroll
  for (int s = 0; s < KNB; ++s) op[s] = base + ti[s];
}

// ---------------- GEMM: UZ(32768 x 2O) = h(32768 x K) * Vt(K x 2O) ----------------
template<int K, int N2>
__global__ __launch_bounds__(256) void gemm_uz_kernel(const float* __restrict__ h,
                                                      const float* __restrict__ Vt,
                                                      float* __restrict__ UZ) {
  constexpr int KC = 32;
  constexpr int NBLK = (N2 + 63) / 64;
  __shared__ __align__(16) float As[KC * 68];   // [k][m]
  __shared__ __align__(16) float Bs[KC * 68];   // [k][j]
  const int m0 = (int)(blockIdx.x / NBLK) * 64;
  const int n0 = (int)(blockIdx.x % NBLK) * 64;
  const int tid = threadIdx.x;
  const int mm = (tid & 15) * 4;
  const int jj = (tid >> 4) * 4;
  float acc[4][4] = {{0.f}};
  for (int k0 = 0; k0 < K; k0 += KC) {
    #pragma unroll
    for (int e = tid; e < 64 * KC; e += 256) {
      int am = e / KC, ac = e - am * KC;
      float v = 0.f;
      if (k0 + ac < K) v = h[(size_t)(m0 + am) * K + k0 + ac];
      As[ac * 68 + am] = v;
    }
    #pragma unroll
    for (int e = tid; e < KC * 64; e += 256) {
      int bj = e & 63, bc = e >> 6;
      float v = 0.f;
      if (k0 + bc < K && n0 + bj < N2) v = Vt[(size_t)(k0 + bc) * N2 + n0 + bj];
      Bs[bc * 68 + bj] = v;
    }
    __syncthreads();
    #pragma unroll
    for (int c = 0; c < KC; ++c) {
      float4 av = *(const float4*)(As + c * 68 + mm);
      float4 bv = *(const float4*)(Bs + c * 68 + jj);
      acc[0][0] = fmaf(av.x, bv.x, acc[0][0]);
      acc[0][1] = fmaf(av.x, bv.y, acc[0][1]);
      acc[0][2] = fmaf(av.x, bv.z, acc[0][2]);
      acc[0][3] = fmaf(av.x, bv.w, acc[0][3]);
      acc[1][0] = fmaf(av.y, bv.x, acc[1][0]);
      acc[1][1] = fmaf(av.y, bv.y, acc[1][1]);
      acc[1][2] = fmaf(av.y, bv.z, acc[1][2]);
      acc[1][3] = fmaf(av.y, bv.w, acc[1][3]);
      acc[2][0] = fmaf(av.z, bv.x, acc[2][0]);
      acc[2][1] = fmaf(av.z, bv.y, acc[2][1]);
      acc[2][2] = fmaf(av.z, bv.z, acc[2][2]);
      acc[2][3] = fmaf(av.z, bv.w, acc[2][3]);
      acc[3][0] = fmaf(av.w, bv.x, acc[3][0]);
      acc[3][1] = fmaf(av.w, bv.y, acc[3][1]);
      acc[3][2] = fmaf(av.w, bv.z, acc[3][2]);
      acc[3][3] = fmaf(av.w, bv.w, acc[3][3]);
    }
    __syncthreads();
  }
  if (n0 + jj < N2) {
    #pragma unroll
    for (int i = 0; i < 4; ++i) {
      float4 v = make_float4(acc[i][0], acc[i][1], acc[i][2], acc[i][3]);
      *(float4*)(UZ + (size_t)(m0 + mm + i) * N2 + n0 + jj) = v;
    }
  }
}

// ---------------- combine: gather u rows, max/min + stats ----------------
template<int O>
__global__ __launch_bounds__(256) void combine_kernel(const float* __restrict__ UZ,
    const int* __restrict__ idx, const float* __restrict__ bias,
    float* __restrict__ ymax, float* __restrict__ ymin, double* __restrict__ sums) {
  constexpr int PPI = 256 / O;          // points per iteration
  constexpr int PPB = TOTPTS / 256;     // 128 points per block
  constexpr int ITERS = PPB / PPI;
  __shared__ double red[256];
  const int o = threadIdx.x % O;
  const int sub = threadIdx.x / O;
  const int base = blockIdx.x * PPB;
  double a1 = 0.0, a2 = 0.0;
  for (int it = 0; it < ITERS; ++it) {
    int n = base + it * PPI + sub;
    const int* ip = idx + (size_t)n * KNB;
    float un = UZ[(size_t)n * (2 * O) + o];
    float zn = UZ[(size_t)n * (2 * O) + O + o];
    float w = zn - un + bias[o];
    float mx = -INFINITY, mn = INFINITY, s1 = 0.f, s2 = 0.f;
    #pragma unroll
    for (int kk = 0; kk < KNB; ++kk) {
      int j = ip[kk];
      float uv = UZ[(size_t)j * (2 * O) + o];
      mx = fmaxf(mx, uv);
      mn = fminf(mn, uv);
      s1 += uv;
      s2 = fmaf(uv, uv, s2);
    }
    ymax[(size_t)n * O + o] = mx + w;
    ymin[(size_t)n * O + o] = mn + w;
    a1 += (double)(s1 + 16.f * w);
    a2 += (double)(s2 + 2.f * w * s1 + 16.f * (w * w));
  }
  red[threadIdx.x] = a1;
  __syncthreads();
  if (threadIdx.x < O) {
    double t = red[threadIdx.x];
    #pragma unroll
    for (int q = 1; q < PPI; ++q) t += red[threadIdx.x + q * O];
    atomicAdd(&sums[threadIdx.x], t);
  }
  __syncthreads();
  red[threadIdx.x] = a2;
  __syncthreads();
  if (threadIdx.x < O) {
    double t = red[threadIdx.x];
    #pragma unroll
    for (int q = 1; q < PPI; ++q) t += red[threadIdx.x + q * O];
    atomicAdd(&sums[O + threadIdx.x], t);
  }
}

// ---------------- apply: BN affine + erf-GELU + endpoint max ----------------
template<int O>
__global__ __launch_bounds__(256) void apply_kernel(const float* __restrict__ ymax,
    const float* __restrict__ ymin, const double* __restrict__ sums,
    const float* __restrict__ g, const float* __restrict__ bt, float* __restrict__ hout) {
  const int tid = blockIdx.x * 256 + threadIdx.x;
  const int o = tid & (O - 1);
  double m = sums[o] * (1.0 / 524288.0);
  double v = fma(-m, m, sums[O + o] * (1.0 / 524288.0));
  float A = g[o] / sqrtf((float)v + 1e-5f);
  float Cc = fmaf(-(float)m, A, bt[o]);
  float r1 = gelu_erf(fmaf(A, ymax[tid], Cc));
  float r2 = gelu_erf(fmaf(A, ymin[tid], Cc));
  hout[tid] = fmaxf(r1, r2);
}

// layer-5 apply, transposes (n,o) -> (bs, o, p, s) via LDS tile
__global__ __launch_bounds__(256) void apply_final_kernel(const float* __restrict__ ymax,
    const float* __restrict__ ymin, const double* __restrict__ sums,
    const float* __restrict__ g, const float* __restrict__ bt, float* __restrict__ out) {
  constexpr int O = 256;
  __shared__ float tile[64 * 65];
  const int bo = blockIdx.x & 3;
  const int bn = blockIdx.x >> 2;
  const int n0 = bn * 64, o0 = bo * 64;
  const int lane = threadIdx.x & 63;
  const int grp = threadIdx.x >> 6;
  {
    const int oc = o0 + lane;
    double m = sums[oc] * (1.0 / 524288.0);
    double v = fma(-m, m, sums[O + oc] * (1.0 / 524288.0));
    float A = g[oc] / sqrtf((float)v + 1e-5f);
    float Cc = fmaf(-(float)m, A, bt[oc]);
    #pragma unroll
    for (int q = 0; q < 16; ++q) {
      int r = grp * 16 + q;
      size_t src = (size_t)(n0 + r) * O + oc;
      float r1 = gelu_erf(fmaf(A, ymax[src], Cc));
      float r2 = gelu_erf(fmaf(A, ymin[src], Cc));
      tile[r * 65 + lane] = fmaxf(r1, r2);
    }
  }
  __syncthreads();
  const int s0 = n0 & 255;
  const int p  = (n0 >> 8) & 31;
  const int bs = n0 >> 13;
  size_t basei = ((size_t)(bs * 256 + o0) * 32 + p) * 256 + s0;
  #pragma unroll
  for (int q = 0; q < 16; ++q) {
    int c = grp * 16 + q;
    out[basei + (size_t)c * 8192 + lane] = tile[lane * 65 + c];
  }
}

// ---------------- launch ----------------
extern "C" void kernel_launch(void* const* d_in, const int* in_sizes, int n_in,
                              void* d_out, int out_size, void* d_ws, size_t ws_size,
                              hipStream_t stream) {
  (void)in_sizes; (void)n_in; (void)out_size; (void)ws_size;
  const float* x   = (const float*)d_in[0];
  const float* W1  = (const float*)d_in[1];
  const float* b1  = (const float*)d_in[2];
  const float* g1  = (const float*)d_in[3];
  const float* bt1 = (const float*)d_in[4];
  const float* W2  = (const float*)d_in[5];
  const float* b2  = (const float*)d_in[6];
  const float* g2  = (const float*)d_in[7];
  const float* bt2 = (const float*)d_in[8];
  const float* W3  = (const float*)d_in[9];
  const float* b3  = (const float*)d_in[10];
  const float* g3  = (const float*)d_in[11];
  const float* bt3 = (const float*)d_in[12];
  const float* W4  = (const float*)d_in[13];
  const float* b4  = (const float*)d_in[14];
  const float* g4  = (const float*)d_in[15];
  const float* bt4 = (const float*)d_in[16];
  const float* W5  = (const float*)d_in[17];
  const float* b5  = (const float*)d_in[18];
  const float* g5  = (const float*)d_in[19];
  const float* bt5 = (const float*)d_in[20];

  float* ws    = (float*)d_ws;
  float* hA    = ws + OFF_HA;
  float* hB    = ws + OFF_HB;
  float* UZ    = ws + OFF_UZ;
  float* ymx   = ws + OFF_YMAX;
  float* ymn   = ws + OFF_YMIN;
  int*   idxb  = (int*)(ws + OFF_IDX);
  float* Vt    = ws + OFF_VT;
  double* sums = (double*)(ws + OFF_SUMS);
  double* nd   = (double*)UZ;    // 64 MiB scratch, free during knn phase
  double* sqd  = (double*)ymx;   // 256 KiB scratch, free during knn phase

  prep_kernel<<<256, 256, 0, stream>>>(x, hA, W1, W2, W3, W4, W5, Vt, sums);

  // layer 1: hA (C=6) -> hB (O=16)
  sq_kernel<6><<<128, 256, 0, stream>>>(hA, sqd);
  dist_kernel<6><<<2048, 256, 0, stream>>>(hA, sqd, nd);
  topk_kernel<<<512, 64, 0, stream>>>(nd, idxb);
  gemm_uz_kernel<6, 32><<<512, 256, 0, stream>>>(hA, Vt + 0, UZ);
  combine_kernel<16><<<256, 256, 0, stream>>>(UZ, idxb, b1, ymx, ymn, sums + 0);
  apply_kernel<16><<<2048, 256, 0, stream>>>(ymx, ymn, sums + 0, g1, bt1, hB);

  // layer 2: hB (C=16) -> hA (O=32)
  sq_kernel<16><<<128, 256, 0, stream>>>(hB, sqd);
  dist_kernel<16><<<2048, 256, 0, stream>>>(hB, sqd, nd);
  topk_kernel<<<512, 64, 0, stream>>>(nd, idxb);
  gemm_uz_kernel<16, 64><<<512, 256, 0, stream>>>(hB, Vt + 192, UZ);
  combine_kernel<32><<<256, 256, 0, stream>>>(UZ, idxb, b2, ymx, ymn, sums + 32);
  apply_kernel<32><<<4096, 256, 0, stream>>>(ymx, ymn, sums + 32, g2, bt2, hA);

  // layer 3: hA (C=32) -> hB (O=64)
  sq_kernel<32><<<128, 256, 0, stream>>>(hA, sqd);
  dist_kernel<32><<<2048, 256, 0, stream>>>(hA, sqd, nd);
  topk_kernel<<<512, 64, 0, stream>>>(nd, idxb);
  gemm_uz_kernel<32, 128><<<1024, 256, 0, stream>>>(hA, Vt + 1216, UZ);
  combine_kernel<64><<<256, 256, 0, stream>>>(UZ, idxb, b3, ymx, ymn, sums + 96);
  apply_kernel<64><<<8192, 256, 0, stream>>>(ymx, ymn, sums + 96, g3, bt3, hB);

  // layer 4: hB (C=64) -> hA (O=128)
  sq_kernel<64><<<128, 256, 0, stream>>>(hB, sqd);
  dist_kernel<64><<<2048, 256, 0, stream>>>(hB, sqd, nd);
  topk_kernel<<<512, 64, 0, stream>>>(nd, idxb);
  gemm_uz_kernel<64, 256><<<2048, 256, 0, stream>>>(hB, Vt + 5312, UZ);
  combine_kernel<128><<<256, 256, 0, stream>>>(UZ, idxb, b4, ymx, ymn, sums + 224);
  apply_kernel<128><<<16384, 256, 0, stream>>>(ymx, ymn, sums + 224, g4, bt4, hA);

  // layer 5: hA (C=128) -> d_out (O=256, transposed layout)
  sq_kernel<128><<<128, 256, 0, stream>>>(hA, sqd);
  dist_kernel<128><<<2048, 256, 0, stream>>>(hA, sqd, nd);
  topk_kernel<<<512, 64, 0, stream>>>(nd, idxb);
  gemm_uz_kernel<128, 512><<<4096, 256, 0, stream>>>(hA, Vt + 21696, UZ);
  combine_kernel<256><<<256, 256, 0, stream>>>(UZ, idxb, b5, ymx, ymn, sums + 480);
  apply_final_kernel<<<2048, 256, 0, stream>>>(ymx, ymn, sums + 480, g5, bt5, (float*)d_out);
}

// Round 4
// 1200.711 us; speedup vs baseline: 1.3191x; 1.0719x over previous
//
#include <hip/hip_runtime.h>
#include <cmath>

#define NPTS 256
#define TOTPTS 32768
#define KNB 16

// ---------------- workspace layout (float-element offsets) ----------------
// UZ region doubles as knn partial-topk buffers (24 MiB) during knn phase.
// YMAX region's head doubles as per-point fp64 sq norms (256 KiB) during knn.
static const size_t OFF_HA   = 0;
static const size_t OFF_HB   = 4194304;
static const size_t OFF_UZ   = 6291456;
static const size_t OFF_YMAX = 23068672;
static const size_t OFF_YMIN = 31457280;
static const size_t OFF_IDX  = 39845888;
static const size_t OFF_VT   = 40370176;
static const size_t OFF_SUMS = 40458240;   // byte offset 161,832,960 (8-aligned)

__device__ __forceinline__ float gelu_erf(float v) {
  return 0.5f * v * (1.0f + erff(v * 0.70710678118654752f));
}

// ---------------- prep: transpose x -> h0, build Vt, zero stats ----------------
__global__ __launch_bounds__(256) void prep_kernel(
    const float* __restrict__ x, float* __restrict__ h0,
    const float* __restrict__ W1, const float* __restrict__ W2, const float* __restrict__ W3,
    const float* __restrict__ W4, const float* __restrict__ W5,
    float* __restrict__ Vt, double* __restrict__ sums) {
  const int stride = gridDim.x * blockDim.x;
  const int tid0 = blockIdx.x * blockDim.x + threadIdx.x;
  // x: (4,6,32,256) -> h0: (128 clouds, 256 pts, 6 ch)
  for (int id = tid0; id < 196608; id += stride) {
    int ch = id % 6;
    int r  = id / 6;            // r = cloud*256 + s
    int s  = r & 255;
    int p  = (r >> 8) & 31;
    int bs = r >> 13;
    h0[id] = x[(((size_t)(bs * 6 + ch) * 32 + p) << 8) + s];
  }
  // Vt[l]: (Cin x 2O), Vt[c*2O + j] = W[j<O ? j*2Cin+c : (j-O)*2Cin+Cin+c]
  for (int id = tid0; id < 87232; id += stride) {
    const float* W; int K, N2, base;
    if (id < 192)        { W = W1; K = 6;   N2 = 32;  base = 0; }
    else if (id < 1216)  { W = W2; K = 16;  N2 = 64;  base = 192; }
    else if (id < 5312)  { W = W3; K = 32;  N2 = 128; base = 1216; }
    else if (id < 21696) { W = W4; K = 64;  N2 = 256; base = 5312; }
    else                 { W = W5; K = 128; N2 = 512; base = 21696; }
    int e = id - base;
    int c = e / N2;
    int j = e - c * N2;
    int O = N2 >> 1;
    Vt[id] = (j < O) ? W[j * 2 * K + c] : W[(j - O) * 2 * K + K + c];
  }
  for (int id = tid0; id < 992; id += stride) sums[id] = 0.0;
}

// ---------------- sq: per-point fp64 squared norm ----------------
template<int C>
__global__ __launch_bounds__(256) void sq_kernel(const float* __restrict__ h,
                                                 double* __restrict__ sqd) {
  const int n = blockIdx.x * 256 + threadIdx.x;
  const float* p = h + (size_t)n * C;
  double q0 = 0.0, q1 = 0.0;
  #pragma unroll
  for (int c = 0; c + 1 < C; c += 2) {
    q0 = fma((double)p[c],   (double)p[c],   q0);
    q1 = fma((double)p[c+1], (double)p[c+1], q1);
  }
  #pragma unroll
  for (int c = C & ~1; c < C; ++c) q0 = fma((double)p[c], (double)p[c], q0);
  sqd[n] = q0 + q1;
}

// ------- dist+partial-topk: fp64 neg-dist 64x64 tile -> per-row-segment top-16 ----
// For tile (i0,j0) of cloud: nd[i][j] = 2*<h_i,h_j> - sq_i - sq_j (fp64 exact key).
// Epilogue: LDS round-trip, threads 0..63 scan their row's 64 cols -> top-16
// (value desc, lowest-index-first among equals) -> partial lists for the merge.
// grid: 128 clouds x 16 tiles, 256 threads.
template<int K>
__global__ __launch_bounds__(256) void dist_topk_kernel(const float* __restrict__ h,
                                                        const double* __restrict__ sqd,
                                                        double* __restrict__ pvals,
                                                        int* __restrict__ pidx) {
  constexpr int KC = (K < 32) ? K : 32;
  __shared__ __align__(16) float As[KC * 68];   // [k][i]
  __shared__ __align__(16) float Bs[KC * 68];   // [k][j]
  __shared__ __align__(16) double tile[64 * 65];
  const int cloud = blockIdx.x >> 4;
  const int tl    = blockIdx.x & 15;
  const int i0 = (tl >> 2) * 64;
  const int j0 = (tl & 3) * 64;
  const float* hb = h + (size_t)cloud * NPTS * K;
  const int tid = threadIdx.x;
  const int mm = (tid & 15) * 4;
  const int jj = (tid >> 4) * 4;
  double acc[4][4] = {{0.0}};
  for (int k0 = 0; k0 < K; k0 += KC) {
    for (int e = tid; e < 64 * KC; e += 256) {
      int am = e / KC, ac = e - am * KC;
      As[ac * 68 + am] = hb[(size_t)(i0 + am) * K + k0 + ac];
    }
    for (int e = tid; e < 64 * KC; e += 256) {
      int bm = e / KC, bc = e - bm * KC;
      Bs[bc * 68 + bm] = hb[(size_t)(j0 + bm) * K + k0 + bc];
    }
    __syncthreads();
    #pragma unroll
    for (int c = 0; c < KC; ++c) {
      float4 av = *(const float4*)(As + c * 68 + mm);
      float4 bv = *(const float4*)(Bs + c * 68 + jj);
      double a0 = (double)av.x, a1 = (double)av.y, a2 = (double)av.z, a3 = (double)av.w;
      double b0 = (double)bv.x, b1 = (double)bv.y, b2 = (double)bv.z, b3 = (double)bv.w;
      acc[0][0] = fma(a0, b0, acc[0][0]);
      acc[0][1] = fma(a0, b1, acc[0][1]);
      acc[0][2] = fma(a0, b2, acc[0][2]);
      acc[0][3] = fma(a0, b3, acc[0][3]);
      acc[1][0] = fma(a1, b0, acc[1][0]);
      acc[1][1] = fma(a1, b1, acc[1][1]);
      acc[1][2] = fma(a1, b2, acc[1][2]);
      acc[1][3] = fma(a1, b3, acc[1][3]);
      acc[2][0] = fma(a2, b0, acc[2][0]);
      acc[2][1] = fma(a2, b1, acc[2][1]);
      acc[2][2] = fma(a2, b2, acc[2][2]);
      acc[2][3] = fma(a2, b3, acc[2][3]);
      acc[3][0] = fma(a3, b0, acc[3][0]);
      acc[3][1] = fma(a3, b1, acc[3][1]);
      acc[3][2] = fma(a3, b2, acc[3][2]);
      acc[3][3] = fma(a3, b3, acc[3][3]);
    }
    __syncthreads();
  }
  {
    double sqi[4], sqj[4];
    #pragma unroll
    for (int r = 0; r < 4; ++r) sqi[r] = sqd[cloud * NPTS + i0 + mm + r];
    #pragma unroll
    for (int s = 0; s < 4; ++s) sqj[s] = sqd[cloud * NPTS + j0 + jj + s];
    #pragma unroll
    for (int r = 0; r < 4; ++r) {
      double* tp = tile + (size_t)(mm + r) * 65 + jj;
      tp[0] = 2.0 * acc[r][0] - sqi[r] - sqj[0];
      tp[1] = 2.0 * acc[r][1] - sqi[r] - sqj[1];
      tp[2] = 2.0 * acc[r][2] - sqi[r] - sqj[2];
      tp[3] = 2.0 * acc[r][3] - sqi[r] - sqj[3];
    }
  }
  __syncthreads();
  if (tid < 64) {
    const double* row = tile + (size_t)tid * 65;
    double tv[KNB]; int ti[KNB];
    #pragma unroll
    for (int s = 0; s < KNB; ++s) { tv[s] = -INFINITY; ti[s] = 0; }
    for (int c = 0; c < 64; ++c) {
      double v = row[c];
      if (v > tv[KNB - 1]) {   // strict > : keeps lowest index on ties
        #pragma unroll
        for (int s = KNB - 1; s >= 1; --s) {
          bool up   = v > tv[s - 1];
          bool here = v > tv[s];
          double pv = tv[s - 1]; int pi = ti[s - 1];
          tv[s] = up ? pv : (here ? v : tv[s]);
          ti[s] = up ? pi : (here ? c : ti[s]);
        }
        if (v > tv[0]) { tv[0] = v; ti[0] = c; }
      }
    }
    const int grow = cloud * NPTS + i0 + tid;   // global row id
    const int jt = j0 >> 6;
    const size_t pb = ((size_t)grow * 4 + jt) * KNB;
    #pragma unroll
    for (int s = 0; s < KNB; ++s) {
      pvals[pb + s] = tv[s];
      pidx[pb + s]  = j0 + ti[s];
    }
  }
}

// ---------------- merge: 4 sorted segment lists -> final top-16 ----------------
__global__ __launch_bounds__(256) void topk_merge_kernel(const double* __restrict__ pvals,
                                                         const int* __restrict__ pidx,
                                                         int* __restrict__ idxout) {
  const int n = blockIdx.x * 256 + (int)threadIdx.x;
  double tv[KNB]; int ti[KNB];
  #pragma unroll
  for (int s = 0; s < KNB; ++s) { tv[s] = -INFINITY; ti[s] = 0; }
  // Process segments in ascending-j order; each list is value-desc with
  // lowest-index-first among equals. Strict-> insertion reproduces the
  // single-pass lax.top_k tie-break exactly.
  for (int jt = 0; jt < 4; ++jt) {
    const size_t pb = ((size_t)n * 4 + jt) * KNB;
    for (int q = 0; q < KNB; ++q) {
      double v = pvals[pb + q];
      if (!(v > tv[KNB - 1])) break;   // desc list: rest rejected too
      int j = pidx[pb + q];
      #pragma unroll
      for (int s = KNB - 1; s >= 1; --s) {
        bool up   = v > tv[s - 1];
        bool here = v > tv[s];
        double pv = tv[s - 1]; int pi = ti[s - 1];
        tv[s] = up ? pv : (here ? v : tv[s]);
        ti[s] = up ? pi : (here ? j : ti[s]);
      }
      if (v > tv[0]) { tv[0] = v; ti[0] = j; }
    }
  }
  const int base = n & ~(NPTS - 1);
  int* op = idxout + (size_t)n * KNB;
  #pragma unroll
  for (int s = 0; s < KNB; ++s) op[s] = base + ti[s];
}

// ---------------- GEMM: UZ(32768 x 2O) = h(32768 x K) * Vt(K x 2O) ----------------
template<int K, int N2>
__global__ __launch_bounds__(256) void gemm_uz_kernel(const float* __restrict__ h,
                                                      const float* __restrict__ Vt,
                                                      float* __restrict__ UZ) {
  constexpr int KC = 32;
  constexpr int NBLK = (N2 + 63) / 64;
  __shared__ __align__(16) float As[KC * 68];   // [k][m]
  __shared__ __align__(16) float Bs[KC * 68];   // [k][j]
  const int m0 = (int)(blockIdx.x / NBLK) * 64;
  const int n0 = (int)(blockIdx.x % NBLK) * 64;
  const int tid = threadIdx.x;
  const int mm = (tid & 15) * 4;
  const int jj = (tid >> 4) * 4;
  float acc[4][4] = {{0.f}};
  for (int k0 = 0; k0 < K; k0 += KC) {
    #pragma unroll
    for (int e = tid; e < 64 * KC; e += 256) {
      int am = e / KC, ac = e - am * KC;
      float v = 0.f;
      if (k0 + ac < K) v = h[(size_t)(m0 + am) * K + k0 + ac];
      As[ac * 68 + am] = v;
    }
    #pragma unroll
    for (int e = tid; e < KC * 64; e += 256) {
      int bj = e & 63, bc = e >> 6;
      float v = 0.f;
      if (k0 + bc < K && n0 + bj < N2) v = Vt[(size_t)(k0 + bc) * N2 + n0 + bj];
      Bs[bc * 68 + bj] = v;
    }
    __syncthreads();
    #pragma unroll
    for (int c = 0; c < KC; ++c) {
      float4 av = *(const float4*)(As + c * 68 + mm);
      float4 bv = *(const float4*)(Bs + c * 68 + jj);
      acc[0][0] = fmaf(av.x, bv.x, acc[0][0]);
      acc[0][1] = fmaf(av.x, bv.y, acc[0][1]);
      acc[0][2] = fmaf(av.x, bv.z, acc[0][2]);
      acc[0][3] = fmaf(av.x, bv.w, acc[0][3]);
      acc[1][0] = fmaf(av.y, bv.x, acc[1][0]);
      acc[1][1] = fmaf(av.y, bv.y, acc[1][1]);
      acc[1][2] = fmaf(av.y, bv.z, acc[1][2]);
      acc[1][3] = fmaf(av.y, bv.w, acc[1][3]);
      acc[2][0] = fmaf(av.z, bv.x, acc[2][0]);
      acc[2][1] = fmaf(av.z, bv.y, acc[2][1]);
      acc[2][2] = fmaf(av.z, bv.z, acc[2][2]);
      acc[2][3] = fmaf(av.z, bv.w, acc[2][3]);
      acc[3][0] = fmaf(av.w, bv.x, acc[3][0]);
      acc[3][1] = fmaf(av.w, bv.y, acc[3][1]);
      acc[3][2] = fmaf(av.w, bv.z, acc[3][2]);
      acc[3][3] = fmaf(av.w, bv.w, acc[3][3]);
    }
    __syncthreads();
  }
  if (n0 + jj < N2) {
    #pragma unroll
    for (int i = 0; i < 4; ++i) {
      float4 v = make_float4(acc[i][0], acc[i][1], acc[i][2], acc[i][3]);
      *(float4*)(UZ + (size_t)(m0 + mm + i) * N2 + n0 + jj) = v;
    }
  }
}

// ---------------- combine: gather u rows, max/min + stats ----------------
template<int O>
__global__ __launch_bounds__(256) void combine_kernel(const float* __restrict__ UZ,
    const int* __restrict__ idx, const float* __restrict__ bias,
    float* __restrict__ ymax, float* __restrict__ ymin, double* __restrict__ sums) {
  constexpr int PPI = 256 / O;          // points per iteration
  constexpr int PPB = TOTPTS / 256;     // 128 points per block
  constexpr int ITERS = PPB / PPI;
  __shared__ double red[256];
  const int o = threadIdx.x % O;
  const int sub = threadIdx.x / O;
  const int base = blockIdx.x * PPB;
  double a1 = 0.0, a2 = 0.0;
  for (int it = 0; it < ITERS; ++it) {
    int n = base + it * PPI + sub;
    const int* ip = idx + (size_t)n * KNB;
    float un = UZ[(size_t)n * (2 * O) + o];
    float zn = UZ[(size_t)n * (2 * O) + O + o];
    float w = zn - un + bias[o];
    float mx = -INFINITY, mn = INFINITY, s1 = 0.f, s2 = 0.f;
    #pragma unroll
    for (int kk = 0; kk < KNB; ++kk) {
      int j = ip[kk];
      float uv = UZ[(size_t)j * (2 * O) + o];
      mx = fmaxf(mx, uv);
      mn = fminf(mn, uv);
      s1 += uv;
      s2 = fmaf(uv, uv, s2);
    }
    ymax[(size_t)n * O + o] = mx + w;
    ymin[(size_t)n * O + o] = mn + w;
    a1 += (double)(s1 + 16.f * w);
    a2 += (double)(s2 + 2.f * w * s1 + 16.f * (w * w));
  }
  red[threadIdx.x] = a1;
  __syncthreads();
  if (threadIdx.x < O) {
    double t = red[threadIdx.x];
    #pragma unroll
    for (int q = 1; q < PPI; ++q) t += red[threadIdx.x + q * O];
    atomicAdd(&sums[threadIdx.x], t);
  }
  __syncthreads();
  red[threadIdx.x] = a2;
  __syncthreads();
  if (threadIdx.x < O) {
    double t = red[threadIdx.x];
    #pragma unroll
    for (int q = 1; q < PPI; ++q) t += red[threadIdx.x + q * O];
    atomicAdd(&sums[O + threadIdx.x], t);
  }
}

// ---------------- apply: BN affine + erf-GELU + endpoint max ----------------
template<int O>
__global__ __launch_bounds__(256) void apply_kernel(const float* __restrict__ ymax,
    const float* __restrict__ ymin, const double* __restrict__ sums,
    const float* __restrict__ g, const float* __restrict__ bt, float* __restrict__ hout) {
  const int tid = blockIdx.x * 256 + threadIdx.x;
  const int o = tid & (O - 1);
  double m = sums[o] * (1.0 / 524288.0);
  double v = fma(-m, m, sums[O + o] * (1.0 / 524288.0));
  float A = g[o] / sqrtf((float)v + 1e-5f);
  float Cc = fmaf(-(float)m, A, bt[o]);
  float r1 = gelu_erf(fmaf(A, ymax[tid], Cc));
  float r2 = gelu_erf(fmaf(A, ymin[tid], Cc));
  hout[tid] = fmaxf(r1, r2);
}

// layer-5 apply, transposes (n,o) -> (bs, o, p, s) via LDS tile
__global__ __launch_bounds__(256) void apply_final_kernel(const float* __restrict__ ymax,
    const float* __restrict__ ymin, const double* __restrict__ sums,
    const float* __restrict__ g, const float* __restrict__ bt, float* __restrict__ out) {
  constexpr int O = 256;
  __shared__ float tile[64 * 65];
  const int bo = blockIdx.x & 3;
  const int bn = blockIdx.x >> 2;
  const int n0 = bn * 64, o0 = bo * 64;
  const int lane = threadIdx.x & 63;
  const int grp = threadIdx.x >> 6;
  {
    const int oc = o0 + lane;
    double m = sums[oc] * (1.0 / 524288.0);
    double v = fma(-m, m, sums[O + oc] * (1.0 / 524288.0));
    float A = g[oc] / sqrtf((float)v + 1e-5f);
    float Cc = fmaf(-(float)m, A, bt[oc]);
    #pragma unroll
    for (int q = 0; q < 16; ++q) {
      int r = grp * 16 + q;
      size_t src = (size_t)(n0 + r) * O + oc;
      float r1 = gelu_erf(fmaf(A, ymax[src], Cc));
      float r2 = gelu_erf(fmaf(A, ymin[src], Cc));
      tile[r * 65 + lane] = fmaxf(r1, r2);
    }
  }
  __syncthreads();
  const int s0 = n0 & 255;
  const int p  = (n0 >> 8) & 31;
  const int bs = n0 >> 13;
  size_t basei = ((size_t)(bs * 256 + o0) * 32 + p) * 256 + s0;
  #pragma unroll
  for (int q = 0; q < 16; ++q) {
    int c = grp * 16 + q;
    out[basei + (size_t)c * 8192 + lane] = tile[lane * 65 + c];
  }
}

// ---------------- launch ----------------
extern "C" void kernel_launch(void* const* d_in, const int* in_sizes, int n_in,
                              void* d_out, int out_size, void* d_ws, size_t ws_size,
                              hipStream_t stream) {
  (void)in_sizes; (void)n_in; (void)out_size; (void)ws_size;
  const float* x   = (const float*)d_in[0];
  const float* W1  = (const float*)d_in[1];
  const float* b1  = (const float*)d_in[2];
  const float* g1  = (const float*)d_in[3];
  const float* bt1 = (const float*)d_in[4];
  const float* W2  = (const float*)d_in[5];
  const float* b2  = (const float*)d_in[6];
  const float* g2  = (const float*)d_in[7];
  const float* bt2 = (const float*)d_in[8];
  const float* W3  = (const float*)d_in[9];
  const float* b3  = (const float*)d_in[10];
  const float* g3  = (const float*)d_in[11];
  const float* bt3 = (const float*)d_in[12];
  const float* W4  = (const float*)d_in[13];
  const float* b4  = (const float*)d_in[14];
  const float* g4  = (const float*)d_in[15];
  const float* bt4 = (const float*)d_in[16];
  const float* W5  = (const float*)d_in[17];
  const float* b5  = (const float*)d_in[18];
  const float* g5  = (const float*)d_in[19];
  const float* bt5 = (const float*)d_in[20];

  float* ws    = (float*)d_ws;
  float* hA    = ws + OFF_HA;
  float* hB    = ws + OFF_HB;
  float* UZ    = ws + OFF_UZ;
  float* ymx   = ws + OFF_YMAX;
  float* ymn   = ws + OFF_YMIN;
  int*   idxb  = (int*)(ws + OFF_IDX);
  float* Vt    = ws + OFF_VT;
  double* sums = (double*)(ws + OFF_SUMS);
  // knn-phase scratch aliases (consumed before gemm_uz overwrites UZ):
  double* pvals = (double*)UZ;                      // 16 MiB: 32768 x 4 x 16 doubles
  int*    pidx  = (int*)(UZ + 4194304);             //  8 MiB: 32768 x 4 x 16 ints
  double* sqd   = (double*)ymx;                     // 256 KiB

  prep_kernel<<<256, 256, 0, stream>>>(x, hA, W1, W2, W3, W4, W5, Vt, sums);

  // layer 1: hA (C=6) -> hB (O=16)
  sq_kernel<6><<<128, 256, 0, stream>>>(hA, sqd);
  dist_topk_kernel<6><<<2048, 256, 0, stream>>>(hA, sqd, pvals, pidx);
  topk_merge_kernel<<<128, 256, 0, stream>>>(pvals, pidx, idxb);
  gemm_uz_kernel<6, 32><<<512, 256, 0, stream>>>(hA, Vt + 0, UZ);
  combine_kernel<16><<<256, 256, 0, stream>>>(UZ, idxb, b1, ymx, ymn, sums + 0);
  apply_kernel<16><<<2048, 256, 0, stream>>>(ymx, ymn, sums + 0, g1, bt1, hB);

  // layer 2: hB (C=16) -> hA (O=32)
  sq_kernel<16><<<128, 256, 0, stream>>>(hB, sqd);
  dist_topk_kernel<16><<<2048, 256, 0, stream>>>(hB, sqd, pvals, pidx);
  topk_merge_kernel<<<128, 256, 0, stream>>>(pvals, pidx, idxb);
  gemm_uz_kernel<16, 64><<<512, 256, 0, stream>>>(hB, Vt + 192, UZ);
  combine_kernel<32><<<256, 256, 0, stream>>>(UZ, idxb, b2, ymx, ymn, sums + 32);
  apply_kernel<32><<<4096, 256, 0, stream>>>(ymx, ymn, sums + 32, g2, bt2, hA);

  // layer 3: hA (C=32) -> hB (O=64)
  sq_kernel<32><<<128, 256, 0, stream>>>(hA, sqd);
  dist_topk_kernel<32><<<2048, 256, 0, stream>>>(hA, sqd, pvals, pidx);
  topk_merge_kernel<<<128, 256, 0, stream>>>(pvals, pidx, idxb);
  gemm_uz_kernel<32, 128><<<1024, 256, 0, stream>>>(hA, Vt + 1216, UZ);
  combine_kernel<64><<<256, 256, 0, stream>>>(UZ, idxb, b3, ymx, ymn, sums + 96);
  apply_kernel<64><<<8192, 256, 0, stream>>>(ymx, ymn, sums + 96, g3, bt3, hB);

  // layer 4: hB (C=64) -> hA (O=128)
  sq_kernel<64><<<128, 256, 0, stream>>>(hB, sqd);
  dist_topk_kernel<64><<<2048, 256, 0, stream>>>(hB, sqd, pvals, pidx);
  topk_merge_kernel<<<128, 256, 0, stream>>>(pvals, pidx, idxb);
  gemm_uz_kernel<64, 256><<<2048, 256, 0, stream>>>(hB, Vt + 5312, UZ);
  combine_kernel<128><<<256, 256, 0, stream>>>(UZ, idxb, b4, ymx, ymn, sums + 224);
  apply_kernel<128><<<16384, 256, 0, stream>>>(ymx, ymn, sums + 224, g4, bt4, hA);

  // layer 5: hA (C=128) -> d_out (O=256, transposed layout)
  sq_kernel<128><<<128, 256, 0, stream>>>(hA, sqd);
  dist_topk_kernel<128><<<2048, 256, 0, stream>>>(hA, sqd, pvals, pidx);
  topk_merge_kernel<<<128, 256, 0, stream>>>(pvals, pidx, idxb);
  gemm_uz_kernel<128, 512><<<4096, 256, 0, stream>>>(hA, Vt + 21696, UZ);
  combine_kernel<256><<<256, 256, 0, stream>>>(UZ, idxb, b5, ymx, ymn, sums + 480);
  apply_final_kernel<<<2048, 256, 0, stream>>>(ymx, ymn, sums + 480, g5, bt5, (float*)d_out);
}

// Round 5
// 1195.410 us; speedup vs baseline: 1.3249x; 1.0044x over previous
//
#include <hip/hip_runtime.h>
#include <cmath>

#define NPTS 256
#define TOTPTS 32768
#define KNB 16

// ---------------- workspace layout (float-element offsets) ----------------
// UZ region doubles as the per-layer fp64 neg-dist matrix (64 MiB) during knn.
// YMAX region's head doubles as per-point fp64 sq norms (256 KiB) during knn.
static const size_t OFF_HA   = 0;
static const size_t OFF_HB   = 4194304;
static const size_t OFF_UZ   = 6291456;
static const size_t OFF_YMAX = 23068672;
static const size_t OFF_YMIN = 31457280;
static const size_t OFF_IDX  = 39845888;
static const size_t OFF_VT   = 40370176;
static const size_t OFF_SUMS = 40458240;   // byte offset 161,832,960 (8-aligned)

__device__ __forceinline__ float gelu_erf(float v) {
  return 0.5f * v * (1.0f + erff(v * 0.70710678118654752f));
}

// ---------------- prep: transpose x -> h0, build Vt, zero stats ----------------
__global__ __launch_bounds__(256) void prep_kernel(
    const float* __restrict__ x, float* __restrict__ h0,
    const float* __restrict__ W1, const float* __restrict__ W2, const float* __restrict__ W3,
    const float* __restrict__ W4, const float* __restrict__ W5,
    float* __restrict__ Vt, double* __restrict__ sums) {
  const int stride = gridDim.x * blockDim.x;
  const int tid0 = blockIdx.x * blockDim.x + threadIdx.x;
  // x: (4,6,32,256) -> h0: (128 clouds, 256 pts, 6 ch)
  for (int id = tid0; id < 196608; id += stride) {
    int ch = id % 6;
    int r  = id / 6;            // r = cloud*256 + s
    int s  = r & 255;
    int p  = (r >> 8) & 31;
    int bs = r >> 13;
    h0[id] = x[(((size_t)(bs * 6 + ch) * 32 + p) << 8) + s];
  }
  // Vt[l]: (Cin x 2O), Vt[c*2O + j] = W[j<O ? j*2Cin+c : (j-O)*2Cin+Cin+c]
  for (int id = tid0; id < 87232; id += stride) {
    const float* W; int K, N2, base;
    if (id < 192)        { W = W1; K = 6;   N2 = 32;  base = 0; }
    else if (id < 1216)  { W = W2; K = 16;  N2 = 64;  base = 192; }
    else if (id < 5312)  { W = W3; K = 32;  N2 = 128; base = 1216; }
    else if (id < 21696) { W = W4; K = 64;  N2 = 256; base = 5312; }
    else                 { W = W5; K = 128; N2 = 512; base = 21696; }
    int e = id - base;
    int c = e / N2;
    int j = e - c * N2;
    int O = N2 >> 1;
    Vt[id] = (j < O) ? W[j * 2 * K + c] : W[(j - O) * 2 * K + K + c];
  }
  for (int id = tid0; id < 992; id += stride) sums[id] = 0.0;
}

// ---------------- sq: per-point fp64 squared norm ----------------
template<int C>
__global__ __launch_bounds__(256) void sq_kernel(const float* __restrict__ h,
                                                 double* __restrict__ sqd) {
  const int n = blockIdx.x * 256 + threadIdx.x;
  const float* p = h + (size_t)n * C;
  double q0 = 0.0, q1 = 0.0;
  #pragma unroll
  for (int c = 0; c + 1 < C; c += 2) {
    q0 = fma((double)p[c],   (double)p[c],   q0);
    q1 = fma((double)p[c+1], (double)p[c+1], q1);
  }
  #pragma unroll
  for (int c = C & ~1; c < C; ++c) q0 = fma((double)p[c], (double)p[c], q0);
  sqd[n] = q0 + q1;
}

// ---------------- dist: fp64 neg-dist matrix, register-tiled GEMM ----------------
// nd[cloud][i][j] = 2*<h_i,h_j> - sq_i - sq_j  (exact ranking key, fp64)
// grid: 128 clouds x 16 tiles (4x4 grid of 64x64 tiles), 256 threads
template<int K>
__global__ __launch_bounds__(256) void dist_kernel(const float* __restrict__ h,
                                                   const double* __restrict__ sqd,
                                                   double* __restrict__ nd) {
  constexpr int KC = (K < 32) ? K : 32;
  __shared__ __align__(16) float As[KC * 68];   // [k][i]
  __shared__ __align__(16) float Bs[KC * 68];   // [k][j]
  const int cloud = blockIdx.x >> 4;
  const int tile  = blockIdx.x & 15;
  const int i0 = (tile >> 2) * 64;
  const int j0 = (tile & 3) * 64;
  const float* hb = h + (size_t)cloud * NPTS * K;
  const int tid = threadIdx.x;
  const int mm = (tid & 15) * 4;
  const int jj = (tid >> 4) * 4;
  double acc[4][4] = {{0.0}};
  for (int k0 = 0; k0 < K; k0 += KC) {
    for (int e = tid; e < 64 * KC; e += 256) {
      int am = e / KC, ac = e - am * KC;
      As[ac * 68 + am] = hb[(size_t)(i0 + am) * K + k0 + ac];
    }
    for (int e = tid; e < 64 * KC; e += 256) {
      int bm = e / KC, bc = e - bm * KC;
      Bs[bc * 68 + bm] = hb[(size_t)(j0 + bm) * K + k0 + bc];
    }
    __syncthreads();
    #pragma unroll
    for (int c = 0; c < KC; ++c) {
      float4 av = *(const float4*)(As + c * 68 + mm);
      float4 bv = *(const float4*)(Bs + c * 68 + jj);
      double a0 = (double)av.x, a1 = (double)av.y, a2 = (double)av.z, a3 = (double)av.w;
      double b0 = (double)bv.x, b1 = (double)bv.y, b2 = (double)bv.z, b3 = (double)bv.w;
      acc[0][0] = fma(a0, b0, acc[0][0]);
      acc[0][1] = fma(a0, b1, acc[0][1]);
      acc[0][2] = fma(a0, b2, acc[0][2]);
      acc[0][3] = fma(a0, b3, acc[0][3]);
      acc[1][0] = fma(a1, b0, acc[1][0]);
      acc[1][1] = fma(a1, b1, acc[1][1]);
      acc[1][2] = fma(a1, b2, acc[1][2]);
      acc[1][3] = fma(a1, b3, acc[1][3]);
      acc[2][0] = fma(a2, b0, acc[2][0]);
      acc[2][1] = fma(a2, b1, acc[2][1]);
      acc[2][2] = fma(a2, b2, acc[2][2]);
      acc[2][3] = fma(a2, b3, acc[2][3]);
      acc[3][0] = fma(a3, b0, acc[3][0]);
      acc[3][1] = fma(a3, b1, acc[3][1]);
      acc[3][2] = fma(a3, b2, acc[3][2]);
      acc[3][3] = fma(a3, b3, acc[3][3]);
    }
    __syncthreads();
  }
  double sqi[4], sqj[4];
  #pragma unroll
  for (int r = 0; r < 4; ++r) sqi[r] = sqd[cloud * NPTS + i0 + mm + r];
  #pragma unroll
  for (int s = 0; s < 4; ++s) sqj[s] = sqd[cloud * NPTS + j0 + jj + s];
  double* orow = nd + (size_t)cloud * NPTS * NPTS;
  #pragma unroll
  for (int r = 0; r < 4; ++r) {
    double v0 = 2.0 * acc[r][0] - sqi[r] - sqj[0];
    double v1 = 2.0 * acc[r][1] - sqi[r] - sqj[1];
    double v2 = 2.0 * acc[r][2] - sqi[r] - sqj[2];
    double v3 = 2.0 * acc[r][3] - sqi[r] - sqj[3];
    double* p = orow + (size_t)(i0 + mm + r) * NPTS + j0 + jj;
    *(double2*)(p)     = make_double2(v0, v1);
    *(double2*)(p + 2) = make_double2(v2, v3);
  }
}

// ------- topk: wave-per-row top-16-SET via tournament (max over k / sums are
// order-invariant, so only the SET of indices matters; fp64 keys make exact
// boundary ties practically impossible). Lane l holds cols 4l..4l+3, sorted
// descending once; 16 rounds of 64-lane butterfly max + winner-head-advance. ---
__global__ __launch_bounds__(256) void topk_wave_kernel(const double* __restrict__ nd,
                                                        int* __restrict__ idxout) {
  const int row  = (blockIdx.x * 256 + (int)threadIdx.x) >> 6;   // one row per wave
  const int lane = threadIdx.x & 63;
  const double* rp = nd + (size_t)row * NPTS + 4 * lane;
  double v[4]; int ci[4];
  {
    double2 p0 = *(const double2*)(rp);
    double2 p1 = *(const double2*)(rp + 2);
    v[0] = p0.x; v[1] = p0.y; v[2] = p1.x; v[3] = p1.y;
    ci[0] = 4 * lane; ci[1] = 4 * lane + 1; ci[2] = 4 * lane + 2; ci[3] = 4 * lane + 3;
  }
  // sort 4 descending (network: (0,1)(2,3)(0,2)(1,3)(1,2))
  #define CE(a, b) { bool sw = v[b] > v[a]; \
    double tv_ = sw ? v[a] : v[b]; v[a] = sw ? v[b] : v[a]; v[b] = tv_; \
    int ti_ = sw ? ci[a] : ci[b]; ci[a] = sw ? ci[b] : ci[a]; ci[b] = ti_; }
  CE(0, 1) CE(2, 3) CE(0, 2) CE(1, 3) CE(1, 2)
  #undef CE
  int head = 0;
  int keep = 0;
  #pragma unroll
  for (int round = 0; round < KNB; ++round) {
    double m = (head < 4) ? v[head & 3] : -INFINITY;
    int gi = (head < 4) ? ci[head & 3] : 0x7fffffff;
    #pragma unroll
    for (int off = 32; off >= 1; off >>= 1) {
      double ov = __shfl_xor(m, off);
      int oi = __shfl_xor(gi, off);
      bool take = (ov > m) || (ov == m && oi < gi);
      m = take ? ov : m;
      gi = take ? oi : gi;
    }
    // all lanes now agree on (m, gi): winner advances its head
    if ((gi >> 2) == lane) head++;
    if (lane == round) keep = gi;
  }
  if (lane < KNB) {
    const int base = row & ~(NPTS - 1);   // cloud base (global point id space)
    idxout[(size_t)row * KNB + lane] = base + keep;
  }
}

// ---------------- GEMM: UZ(32768 x 2O) = h(32768 x K) * Vt(K x 2O) ----------------
template<int K, int N2>
__global__ __launch_bounds__(256) void gemm_uz_kernel(const float* __restrict__ h,
                                                      const float* __restrict__ Vt,
                                                      float* __restrict__ UZ) {
  constexpr int KC = 32;
  constexpr int NBLK = (N2 + 63) / 64;
  __shared__ __align__(16) float As[KC * 68];   // [k][m]
  __shared__ __align__(16) float Bs[KC * 68];   // [k][j]
  const int m0 = (int)(blockIdx.x / NBLK) * 64;
  const int n0 = (int)(blockIdx.x % NBLK) * 64;
  const int tid = threadIdx.x;
  const int mm = (tid & 15) * 4;
  const int jj = (tid >> 4) * 4;
  float acc[4][4] = {{0.f}};
  for (int k0 = 0; k0 < K; k0 += KC) {
    #pragma unroll
    for (int e = tid; e < 64 * KC; e += 256) {
      int am = e / KC, ac = e - am * KC;
      float v = 0.f;
      if (k0 + ac < K) v = h[(size_t)(m0 + am) * K + k0 + ac];
      As[ac * 68 + am] = v;
    }
    #pragma unroll
    for (int e = tid; e < KC * 64; e += 256) {
      int bj = e & 63, bc = e >> 6;
      float v = 0.f;
      if (k0 + bc < K && n0 + bj < N2) v = Vt[(size_t)(k0 + bc) * N2 + n0 + bj];
      Bs[bc * 68 + bj] = v;
    }
    __syncthreads();
    #pragma unroll
    for (int c = 0; c < KC; ++c) {
      float4 av = *(const float4*)(As + c * 68 + mm);
      float4 bv = *(const float4*)(Bs + c * 68 + jj);
      acc[0][0] = fmaf(av.x, bv.x, acc[0][0]);
      acc[0][1] = fmaf(av.x, bv.y, acc[0][1]);
      acc[0][2] = fmaf(av.x, bv.z, acc[0][2]);
      acc[0][3] = fmaf(av.x, bv.w, acc[0][3]);
      acc[1][0] = fmaf(av.y, bv.x, acc[1][0]);
      acc[1][1] = fmaf(av.y, bv.y, acc[1][1]);
      acc[1][2] = fmaf(av.y, bv.z, acc[1][2]);
      acc[1][3] = fmaf(av.y, bv.w, acc[1][3]);
      acc[2][0] = fmaf(av.z, bv.x, acc[2][0]);
      acc[2][1] = fmaf(av.z, bv.y, acc[2][1]);
      acc[2][2] = fmaf(av.z, bv.z, acc[2][2]);
      acc[2][3] = fmaf(av.z, bv.w, acc[2][3]);
      acc[3][0] = fmaf(av.w, bv.x, acc[3][0]);
      acc[3][1] = fmaf(av.w, bv.y, acc[3][1]);
      acc[3][2] = fmaf(av.w, bv.z, acc[3][2]);
      acc[3][3] = fmaf(av.w, bv.w, acc[3][3]);
    }
    __syncthreads();
  }
  if (n0 + jj < N2) {
    #pragma unroll
    for (int i = 0; i < 4; ++i) {
      float4 v = make_float4(acc[i][0], acc[i][1], acc[i][2], acc[i][3]);
      *(float4*)(UZ + (size_t)(m0 + mm + i) * N2 + n0 + jj) = v;
    }
  }
}

// ---------------- combine: gather u rows, max/min + stats ----------------
template<int O>
__global__ __launch_bounds__(256) void combine_kernel(const float* __restrict__ UZ,
    const int* __restrict__ idx, const float* __restrict__ bias,
    float* __restrict__ ymax, float* __restrict__ ymin, double* __restrict__ sums) {
  constexpr int PPI = 256 / O;          // points per iteration
  constexpr int PPB = TOTPTS / 256;     // 128 points per block
  constexpr int ITERS = PPB / PPI;
  __shared__ double red[256];
  const int o = threadIdx.x % O;
  const int sub = threadIdx.x / O;
  const int base = blockIdx.x * PPB;
  double a1 = 0.0, a2 = 0.0;
  for (int it = 0; it < ITERS; ++it) {
    int n = base + it * PPI + sub;
    const int* ip = idx + (size_t)n * KNB;
    float un = UZ[(size_t)n * (2 * O) + o];
    float zn = UZ[(size_t)n * (2 * O) + O + o];
    float w = zn - un + bias[o];
    float mx = -INFINITY, mn = INFINITY, s1 = 0.f, s2 = 0.f;
    #pragma unroll
    for (int kk = 0; kk < KNB; ++kk) {
      int j = ip[kk];
      float uv = UZ[(size_t)j * (2 * O) + o];
      mx = fmaxf(mx, uv);
      mn = fminf(mn, uv);
      s1 += uv;
      s2 = fmaf(uv, uv, s2);
    }
    ymax[(size_t)n * O + o] = mx + w;
    ymin[(size_t)n * O + o] = mn + w;
    a1 += (double)(s1 + 16.f * w);
    a2 += (double)(s2 + 2.f * w * s1 + 16.f * (w * w));
  }
  red[threadIdx.x] = a1;
  __syncthreads();
  if (threadIdx.x < O) {
    double t = red[threadIdx.x];
    #pragma unroll
    for (int q = 1; q < PPI; ++q) t += red[threadIdx.x + q * O];
    atomicAdd(&sums[threadIdx.x], t);
  }
  __syncthreads();
  red[threadIdx.x] = a2;
  __syncthreads();
  if (threadIdx.x < O) {
    double t = red[threadIdx.x];
    #pragma unroll
    for (int q = 1; q < PPI; ++q) t += red[threadIdx.x + q * O];
    atomicAdd(&sums[O + threadIdx.x], t);
  }
}

// ---------------- apply: BN affine + erf-GELU + endpoint max ----------------
template<int O>
__global__ __launch_bounds__(256) void apply_kernel(const float* __restrict__ ymax,
    const float* __restrict__ ymin, const double* __restrict__ sums,
    const float* __restrict__ g, const float* __restrict__ bt, float* __restrict__ hout) {
  const int tid = blockIdx.x * 256 + threadIdx.x;
  const int o = tid & (O - 1);
  double m = sums[o] * (1.0 / 524288.0);
  double v = fma(-m, m, sums[O + o] * (1.0 / 524288.0));
  float A = g[o] / sqrtf((float)v + 1e-5f);
  float Cc = fmaf(-(float)m, A, bt[o]);
  float r1 = gelu_erf(fmaf(A, ymax[tid], Cc));
  float r2 = gelu_erf(fmaf(A, ymin[tid], Cc));
  hout[tid] = fmaxf(r1, r2);
}

// layer-5 apply, transposes (n,o) -> (bs, o, p, s) via LDS tile
__global__ __launch_bounds__(256) void apply_final_kernel(const float* __restrict__ ymax,
    const float* __restrict__ ymin, const double* __restrict__ sums,
    const float* __restrict__ g, const float* __restrict__ bt, float* __restrict__ out) {
  constexpr int O = 256;
  __shared__ float tile[64 * 65];
  const int bo = blockIdx.x & 3;
  const int bn = blockIdx.x >> 2;
  const int n0 = bn * 64, o0 = bo * 64;
  const int lane = threadIdx.x & 63;
  const int grp = threadIdx.x >> 6;
  {
    const int oc = o0 + lane;
    double m = sums[oc] * (1.0 / 524288.0);
    double v = fma(-m, m, sums[O + oc] * (1.0 / 524288.0));
    float A = g[oc] / sqrtf((float)v + 1e-5f);
    float Cc = fmaf(-(float)m, A, bt[oc]);
    #pragma unroll
    for (int q = 0; q < 16; ++q) {
      int r = grp * 16 + q;
      size_t src = (size_t)(n0 + r) * O + oc;
      float r1 = gelu_erf(fmaf(A, ymax[src], Cc));
      float r2 = gelu_erf(fmaf(A, ymin[src], Cc));
      tile[r * 65 + lane] = fmaxf(r1, r2);
    }
  }
  __syncthreads();
  const int s0 = n0 & 255;
  const int p  = (n0 >> 8) & 31;
  const int bs = n0 >> 13;
  size_t basei = ((size_t)(bs * 256 + o0) * 32 + p) * 256 + s0;
  #pragma unroll
  for (int q = 0; q < 16; ++q) {
    int c = grp * 16 + q;
    out[basei + (size_t)c * 8192 + lane] = tile[lane * 65 + c];
  }
}

// ---------------- launch ----------------
extern "C" void kernel_launch(void* const* d_in, const int* in_sizes, int n_in,
                              void* d_out, int out_size, void* d_ws, size_t ws_size,
                              hipStream_t stream) {
  (void)in_sizes; (void)n_in; (void)out_size; (void)ws_size;
  const float* x   = (const float*)d_in[0];
  const float* W1  = (const float*)d_in[1];
  const float* b1  = (const float*)d_in[2];
  const float* g1  = (const float*)d_in[3];
  const float* bt1 = (const float*)d_in[4];
  const float* W2  = (const float*)d_in[5];
  const float* b2  = (const float*)d_in[6];
  const float* g2  = (const float*)d_in[7];
  const float* bt2 = (const float*)d_in[8];
  const float* W3  = (const float*)d_in[9];
  const float* b3  = (const float*)d_in[10];
  const float* g3  = (const float*)d_in[11];
  const float* bt3 = (const float*)d_in[12];
  const float* W4  = (const float*)d_in[13];
  const float* b4  = (const float*)d_in[14];
  const float* g4  = (const float*)d_in[15];
  const float* bt4 = (const float*)d_in[16];
  const float* W5  = (const float*)d_in[17];
  const float* b5  = (const float*)d_in[18];
  const float* g5  = (const float*)d_in[19];
  const float* bt5 = (const float*)d_in[20];

  float* ws    = (float*)d_ws;
  float* hA    = ws + OFF_HA;
  float* hB    = ws + OFF_HB;
  float* UZ    = ws + OFF_UZ;
  float* ymx   = ws + OFF_YMAX;
  float* ymn   = ws + OFF_YMIN;
  int*   idxb  = (int*)(ws + OFF_IDX);
  float* Vt    = ws + OFF_VT;
  double* sums = (double*)(ws + OFF_SUMS);
  double* nd   = (double*)UZ;    // 64 MiB scratch, free during knn phase
  double* sqd  = (double*)ymx;   // 256 KiB scratch, free during knn phase

  prep_kernel<<<256, 256, 0, stream>>>(x, hA, W1, W2, W3, W4, W5, Vt, sums);

  // layer 1: hA (C=6) -> hB (O=16)
  sq_kernel<6><<<128, 256, 0, stream>>>(hA, sqd);
  dist_kernel<6><<<2048, 256, 0, stream>>>(hA, sqd, nd);
  topk_wave_kernel<<<8192, 256, 0, stream>>>(nd, idxb);
  gemm_uz_kernel<6, 32><<<512, 256, 0, stream>>>(hA, Vt + 0, UZ);
  combine_kernel<16><<<256, 256, 0, stream>>>(UZ, idxb, b1, ymx, ymn, sums + 0);
  apply_kernel<16><<<2048, 256, 0, stream>>>(ymx, ymn, sums + 0, g1, bt1, hB);

  // layer 2: hB (C=16) -> hA (O=32)
  sq_kernel<16><<<128, 256, 0, stream>>>(hB, sqd);
  dist_kernel<16><<<2048, 256, 0, stream>>>(hB, sqd, nd);
  topk_wave_kernel<<<8192, 256, 0, stream>>>(nd, idxb);
  gemm_uz_kernel<16, 64><<<512, 256, 0, stream>>>(hB, Vt + 192, UZ);
  combine_kernel<32><<<256, 256, 0, stream>>>(UZ, idxb, b2, ymx, ymn, sums + 32);
  apply_kernel<32><<<4096, 256, 0, stream>>>(ymx, ymn, sums + 32, g2, bt2, hA);

  // layer 3: hA (C=32) -> hB (O=64)
  sq_kernel<32><<<128, 256, 0, stream>>>(hA, sqd);
  dist_kernel<32><<<2048, 256, 0, stream>>>(hA, sqd, nd);
  topk_wave_kernel<<<8192, 256, 0, stream>>>(nd, idxb);
  gemm_uz_kernel<32, 128><<<1024, 256, 0, stream>>>(hA, Vt + 1216, UZ);
  combine_kernel<64><<<256, 256, 0, stream>>>(UZ, idxb, b3, ymx, ymn, sums + 96);
  apply_kernel<64><<<8192, 256, 0, stream>>>(ymx, ymn, sums + 96, g3, bt3, hB);

  // layer 4: hB (C=64) -> hA (O=128)
  sq_kernel<64><<<128, 256, 0, stream>>>(hB, sqd);
  dist_kernel<64><<<2048, 256, 0, stream>>>(hB, sqd, nd);
  topk_wave_kernel<<<8192, 256, 0, stream>>>(nd, idxb);
  gemm_uz_kernel<64, 256><<<2048, 256, 0, stream>>>(hB, Vt + 5312, UZ);
  combine_kernel<128><<<256, 256, 0, stream>>>(UZ, idxb, b4, ymx, ymn, sums + 224);
  apply_kernel<128><<<16384, 256, 0, stream>>>(ymx, ymn, sums + 224, g4, bt4, hA);

  // layer 5: hA (C=128) -> d_out (O=256, transposed layout)
  sq_kernel<128><<<128, 256, 0, stream>>>(hA, sqd);
  dist_kernel<128><<<2048, 256, 0, stream>>>(hA, sqd, nd);
  topk_wave_kernel<<<8192, 256, 0, stream>>>(nd, idxb);
  gemm_uz_kernel<128, 512><<<4096, 256, 0, stream>>>(hA, Vt + 21696, UZ);
  combine_kernel<256><<<256, 256, 0, stream>>>(UZ, idxb, b5, ymx, ymn, sums + 480);
  apply_final_kernel<<<2048, 256, 0, stream>>>(ymx, ymn, sums + 480, g5, bt5, (float*)d_out);
}